// Round 2
// baseline (667.095 us; speedup 1.0000x reference)
//
#include <hip/hip_runtime.h>

namespace {
constexpr int kB = 64;
constexpr int kT = 500;
constexpr int kN = 4096;
constexpr int kThreads = 1024;
constexpr int kPer = kN / kThreads;     // 4 neurons per thread
constexpr int kWaves = kThreads / 64;   // 16
constexpr float kAlpha = 0.1f;          // DT/TAU
}

typedef float f4 __attribute__((ext_vector_type(4)));

__device__ __forceinline__ float fast_tanh(float x) {
    x = fminf(fmaxf(x, -15.f), 15.f);
    const float e = __expf(2.f * x);
    return 1.f - __fdividef(2.f, e + 1.f);
}

__global__ __launch_bounds__(kThreads, 1)
void lowrank_rnn_kernel(const float* __restrict__ input,
                        const float* __restrict__ noise_rec,
                        const float* __restrict__ noise_inp,
                        const float* __restrict__ L,
                        float* __restrict__ out)
{
    const int b    = blockIdx.x;
    const int tid  = threadIdx.x;
    const int lane = tid & 63;
    const int wid  = tid >> 6;
    const int n0   = tid * kPer;

    // double-buffered wave partials -> one __syncthreads per step
    __shared__ float2 part[2][kWaves];

    // L is (N, 8): [I0 I1 I2 | U0 U1 | V0 V1 | W]
    float I0[kPer], I1[kPer], I2[kPer], U0[kPer], U1[kPer], V0[kPer], V1[kPer];
#pragma unroll
    for (int j = 0; j < kPer; ++j) {
        const f4 w0 = *reinterpret_cast<const f4*>(L + (size_t)(n0 + j) * 8);
        const f4 w1 = *reinterpret_cast<const f4*>(L + (size_t)(n0 + j) * 8 + 4);
        I0[j] = w0.x; I1[j] = w0.y; I2[j] = w0.z; U0[j] = w0.w;
        U1[j] = w1.x; V0[j] = w1.y; V1[j] = w1.z;
    }

    float x[kPer];
#pragma unroll
    for (int j = 0; j < kPer; ++j) x[j] = 0.f;

    float* out_b = out + (size_t)b * (kT + 1) * kN;
    {   // hidden[b, 0, :] = 0
        f4 z4 = {0.f, 0.f, 0.f, 0.f};
        __builtin_nontemporal_store(z4, reinterpret_cast<f4*>(out_b + n0));
    }

    const float* nr   = noise_rec + (size_t)b * kT * kN + n0;
    const float* in_b = input     + (size_t)b * kT * 3;
    const float* ni_b = noise_inp + (size_t)b * kT * 3;

    // prefetch t = 0
    f4 nr_cur = __builtin_nontemporal_load(reinterpret_cast<const f4*>(nr));
    float u0 = in_b[0] + ni_b[0];
    float u1 = in_b[1] + ni_b[1];
    float u2 = in_b[2] + ni_b[2];

    for (int t = 0; t < kT; ++t) {
        // ---- prefetch step t+1 (independent of state) ----
        const int tn = (t + 1 < kT) ? t + 1 : t;
        const f4 nr_nxt = __builtin_nontemporal_load(
            reinterpret_cast<const f4*>(nr + (size_t)tn * kN));
        const float un0 = in_b[tn * 3 + 0] + ni_b[tn * 3 + 0];
        const float un1 = in_b[tn * 3 + 1] + ni_b[tn * 3 + 1];
        const float un2 = in_b[tn * 3 + 2] + ni_b[tn * 3 + 2];

        // ---- z = tanh(x) @ V   (per-thread partial over 4 neurons) ----
        float z0p = 0.f, z1p = 0.f;
#pragma unroll
        for (int j = 0; j < kPer; ++j) {
            const float phi = fast_tanh(x[j]);
            z0p = __fmaf_rn(phi, V0[j], z0p);
            z1p = __fmaf_rn(phi, V1[j], z1p);
        }
        // wave reduce (64 lanes)
#pragma unroll
        for (int off = 32; off > 0; off >>= 1) {
            z0p += __shfl_xor(z0p, off, 64);
            z1p += __shfl_xor(z1p, off, 64);
        }
        if (lane == 0) part[t & 1][wid] = make_float2(z0p, z1p);
        __syncthreads();
        float z0 = 0.f, z1 = 0.f;
#pragma unroll
        for (int w = 0; w < kWaves; ++w) {
            const float2 p = part[t & 1][w];
            z0 += p.x; z1 += p.y;
        }

        // ---- state update + output ----
        const float nrv[4] = {nr_cur.x, nr_cur.y, nr_cur.z, nr_cur.w};
        f4 xo;
#pragma unroll
        for (int j = 0; j < kPer; ++j) {
            float rec = (U0[j] * z0 + U1[j] * z1) * (1.f / kN);
            rec = __fmaf_rn(u0, I0[j], rec);
            rec = __fmaf_rn(u1, I1[j], rec);
            rec = __fmaf_rn(u2, I2[j], rec);
            x[j] = 0.9f * x[j] + kAlpha * (rec + nrv[j]);
            xo[j] = x[j];
        }
        __builtin_nontemporal_store(
            xo, reinterpret_cast<f4*>(out_b + (size_t)(t + 1) * kN + n0));

        nr_cur = nr_nxt;
        u0 = un0; u1 = un1; u2 = un2;
    }
}

extern "C" void kernel_launch(void* const* d_in, const int* in_sizes, int n_in,
                              void* d_out, int out_size, void* d_ws, size_t ws_size,
                              hipStream_t stream) {
    const float* input     = (const float*)d_in[0];
    const float* noise_rec = (const float*)d_in[1];
    const float* noise_inp = (const float*)d_in[2];
    const float* L         = (const float*)d_in[3];
    float* out             = (float*)d_out;
    lowrank_rnn_kernel<<<kB, kThreads, 0, stream>>>(input, noise_rec, noise_inp, L, out);
}